// Round 19
// baseline (53.471 us; speedup 1.0000x reference)
//
#include <hip/hip_runtime.h>
#include <hip/hip_bf16.h>

typedef __attribute__((ext_vector_type(8)))  short short8;
typedef __attribute__((ext_vector_type(4)))  float f32x4;
typedef __attribute__((ext_vector_type(16))) float f32x16;

#define CIN   16
#define HH    256
#define WW    256
#define OHH   254
#define OWW   254
#define HW    (HH * WW)

// LDS row-ring: [2 cihalf][16 slot][36 w][8 ci] bf16, 16B cells (R7/R13-proven
// geometry: px stride 16B -> conflict-free b128). Half stride padded +16B.
#define SLOTU  (36 * 8)              // 288 ushorts per patch row
#define HALF_R (16 * SLOTU + 8)      // 4616 ushorts per ci-half

__device__ __forceinline__ ushort f2bf(float f) {
    unsigned u = __builtin_bit_cast(unsigned, f);
    unsigned r = (u + 0x7fffu + ((u >> 16) & 1u)) >> 16;
    return (ushort)r;
}

// fast tanh(tanh(x)): exp2-based (verified absmax 3.9e-3 in R1-R18)
__device__ __forceinline__ float dtanh2(float x) {
    const float K = 2.8853900817779268f;   // 2*log2(e)
    float xc = fminf(fmaxf(x, -9.0f), 9.0f);
    float e1 = __builtin_amdgcn_exp2f(K * xc);
    float t1 = 1.0f - 2.0f * __builtin_amdgcn_rcpf(e1 + 1.0f);
    float e2 = __builtin_amdgcn_exp2f(K * t1);
    return 1.0f - 2.0f * __builtin_amdgcn_rcpf(e2 + 1.0f);
}

// tree min over 16 accumulator elements (depth 4 vs 15-deep serial chain)
__device__ __forceinline__ float rmin16(f32x16 a) {
    float t0 = fminf(fminf(a[0],  a[1]),  fminf(a[2],  a[3]));
    float t1 = fminf(fminf(a[4],  a[5]),  fminf(a[6],  a[7]));
    float t2 = fminf(fminf(a[8],  a[9]),  fminf(a[10], a[11]));
    float t3 = fminf(fminf(a[12], a[13]), fminf(a[14], a[15]));
    return fminf(fminf(t0, t1), fminf(t2, t3));
}

// Weights fp32 OIHW [64][16][3][3] -> 32x32x16 A-fragments (R9-proven):
// wfrag[tap][j][lane][r]: channel row = j*32+(lane&31), ci = 8*(lane>>5)+r.
__global__ void prep_weights(const float* __restrict__ wsrc, ushort* __restrict__ wfrag) {
    int idx = blockIdx.x * 256 + threadIdx.x;
    if (idx >= 9216) return;
    int r    = idx & 7;
    int lane = (idx >> 3) & 63;
    int j    = (idx >> 9) & 1;
    int tap  = idx >> 10;                 // 0..8
    int ci   = 8 * (lane >> 5) + r;
    int co   = j * 32 + (lane & 31);
    int kh   = tap / 3, kw = tap - 3 * kh;
    wfrag[idx] = f2bf(wsrc[(co * CIN + ci) * 9 + kh * 3 + kw]);
}

// 64-row strips, 1024 blocks = EXACTLY 4/CU (zero tail), 16 waves/CU.
// Single prefetch set keeps live regs ~114 < 128 cap of (256,4).
// R2/R6/R10 lesson: WRITE_SIZE is the spill tripwire.
__global__ __launch_bounds__(256, 4) void conv_min_tanh(
        const float* __restrict__ x, const ushort* __restrict__ wfrag,
        const float* __restrict__ bias, float* __restrict__ out) {
    __shared__ ushort ring[2 * HALF_R];      // 18,464 B
    __shared__ ushort mp[2][2][4][32];       // 1,024 B (parity-double-buffered)

    const int tid   = threadIdx.x;
    const int ow0   = blockIdx.x * 32;
    const int hbase = blockIdx.y * 64;       // strip base row
    const int n     = blockIdx.z;
    const float* xb = x + (size_t)n * CIN * HW;

    // ---- prologue: stage patch rows hbase..hbase+7 (chunks 0,1) inline ----
    auto stage_inline = [&](int pos) {       // pos = lr*36 + ciq*9 + w4, lr 0..7
        int lr_  = pos / 36;
        int rm_  = pos - lr_ * 36;
        int ciq_ = rm_ / 9;
        int w4_  = rm_ - ciq_ * 9;
        int hg  = min(hbase + lr_, HH - 1);
        int wg_ = min(ow0 + 4 * w4_, WW - 4);
        const float* src = xb + (size_t)(ciq_ * 4) * HW + hg * WW + wg_;
        f32x4 v0 = *reinterpret_cast<const f32x4*>(src);
        f32x4 v1 = *reinterpret_cast<const f32x4*>(src + HW);
        f32x4 v2 = *reinterpret_cast<const f32x4*>(src + 2 * HW);
        f32x4 v3 = *reinterpret_cast<const f32x4*>(src + 3 * HW);
        ushort* dst = &ring[(ciq_ >> 1) * HALF_R + lr_ * SLOTU + (4 * w4_) * 8 + (ciq_ & 1) * 4];
#pragma unroll
        for (int e = 0; e < 4; ++e) {
            unsigned lo, hi;
            asm("v_cvt_pk_bf16_f32 %0, %1, %2" : "=v"(lo) : "v"(v0[e]), "v"(v1[e]));
            asm("v_cvt_pk_bf16_f32 %0, %1, %2" : "=v"(hi) : "v"(v2[e]), "v"(v3[e]));
            uint2 pk; pk.x = lo; pk.y = hi;
            *reinterpret_cast<uint2*>(dst + e * 8) = pk;
        }
    };
    stage_inline(tid);
    if (tid < 32) stage_inline(tid + 256);   // 288 positions = 8 rows

    // ---- steady-state stage constants (threads 0..143, 1 position each) ----
    const bool sa = (tid < 144);
    const int lr  = tid / 36;                // 0..3 within chunk
    const int rm  = tid - lr * 36;
    const int ciq = rm / 9;
    const int w4  = rm - ciq * 9;
    const int wg  = min(ow0 + 4 * w4, WW - 4);
    const float* gbase = xb + (size_t)(ciq * 4) * HW + wg;
    ushort* sdst = &ring[(ciq >> 1) * HALF_R + (4 * w4) * 8 + (ciq & 1) * 4];

    f32x4 ra0 = {}, ra1 = {}, ra2 = {}, ra3 = {};

#define ISSUE(cc)                                                              \
    if (sa) {                                                                  \
        int hg = min(hbase + 4 * (cc) + lr, HH - 1);                           \
        const float* s_ = gbase + hg * WW;                                     \
        asm volatile("global_load_dwordx4 %0, %1, off" : "=v"(ra0) : "v"(s_) : "memory");           \
        asm volatile("global_load_dwordx4 %0, %1, off" : "=v"(ra1) : "v"(s_ + HW) : "memory");      \
        asm volatile("global_load_dwordx4 %0, %1, off" : "=v"(ra2) : "v"(s_ + 2 * HW) : "memory");  \
        asm volatile("global_load_dwordx4 %0, %1, off" : "=v"(ra3) : "v"(s_ + 3 * HW) : "memory");  \
    }

#define WRITEBK(cc)                                                            \
    if (sa) {                                                                  \
        ushort* d_ = sdst + ((4 * (cc) + lr) & 15) * SLOTU;                    \
        _Pragma("unroll")                                                      \
        for (int e = 0; e < 4; ++e) {                                          \
            unsigned lo_, hi_;                                                 \
            asm("v_cvt_pk_bf16_f32 %0, %1, %2" : "=v"(lo_) : "v"(ra0[e]), "v"(ra1[e]));  \
            asm("v_cvt_pk_bf16_f32 %0, %1, %2" : "=v"(hi_) : "v"(ra2[e]), "v"(ra3[e]));  \
            uint2 pk_; pk_.x = lo_; pk_.y = hi_;                               \
            *reinterpret_cast<uint2*>(d_ + e * 8) = pk_;                       \
        }                                                                      \
    }

    ISSUE(2);                                // 1-deep prefetch (4 loads in flight)

    // ---- weights (A-operand) + bias while loads fly ----
    const int lane  = tid & 63;
    const int wid   = tid >> 6;
    const int jw    = wid & 1;               // channel tile
    const int rq    = wid >> 1;              // row pair within chunk
    const int px    = lane & 31;
    const int khalf = lane >> 5;
    short8 wf[9];
#pragma unroll
    for (int tap = 0; tap < 9; ++tap)
        wf[tap] = *reinterpret_cast<const short8*>(wfrag + ((tap * 2 + jw) * 64 + lane) * 8);
    f32x16 bi;                               // D row = (r&3)+8*(r>>2)+4*khalf
#pragma unroll
    for (int q4 = 0; q4 < 4; ++q4) {
        f32x4 b = *reinterpret_cast<const f32x4*>(bias + jw * 32 + 4 * khalf + 8 * q4);
#pragma unroll
        for (int s = 0; s < 4; ++s) bi[q4 * 4 + s] = b[s];
    }
    const ushort* bptr = &ring[khalf * HALF_R + px * 8];

    asm volatile("s_waitcnt lgkmcnt(0)" ::: "memory");
    __builtin_amdgcn_s_barrier();            // rows 0..7 ready; loads stay in flight

    // ---- 16 chunks: compute(c) | vmcnt(0) write(c+2) issue(c+3) | barrier | out(c) ----
#pragma unroll 2
    for (int c = 0; c < 16; ++c) {
        // merged-row compute: rows R0=4c+2rq, R0+1; 4 patch rows, 12 reads, 18 MFMA
        {
            const int R0 = 4 * c + 2 * rq;
            f32x16 a0 = bi, a1 = bi;
#pragma unroll
            for (int t = 0; t < 4; ++t) {
                const ushort* rp = bptr + ((R0 + t) & 15) * SLOTU;
                short8 f0 = *reinterpret_cast<const short8*>(rp);
                short8 f1 = *reinterpret_cast<const short8*>(rp + 8);
                short8 f2 = *reinterpret_cast<const short8*>(rp + 16);
                if (t < 3) {
                    a0 = __builtin_amdgcn_mfma_f32_32x32x16_bf16(wf[t * 3 + 0], f0, a0, 0, 0, 0);
                    a0 = __builtin_amdgcn_mfma_f32_32x32x16_bf16(wf[t * 3 + 1], f1, a0, 0, 0, 0);
                    a0 = __builtin_amdgcn_mfma_f32_32x32x16_bf16(wf[t * 3 + 2], f2, a0, 0, 0, 0);
                }
                if (t >= 1) {
                    a1 = __builtin_amdgcn_mfma_f32_32x32x16_bf16(wf[(t - 1) * 3 + 0], f0, a1, 0, 0, 0);
                    a1 = __builtin_amdgcn_mfma_f32_32x32x16_bf16(wf[(t - 1) * 3 + 1], f1, a1, 0, 0, 0);
                    a1 = __builtin_amdgcn_mfma_f32_32x32x16_bf16(wf[(t - 1) * 3 + 2], f2, a1, 0, 0, 0);
                }
            }
            float v0 = rmin16(a0), v1 = rmin16(a1);
            v0 = fminf(v0, __shfl_xor(v0, 32, 64));
            v1 = fminf(v1, __shfl_xor(v1, 32, 64));
            if (lane < 32) {
                mp[c & 1][jw][2 * rq + 0][px] = f2bf(v0);
                mp[c & 1][jw][2 * rq + 1][px] = f2bf(v1);
            }
        }

        // drain the single outstanding chunk (had full compute to land), write, reissue
        if (c < 15) {
            asm volatile("s_waitcnt vmcnt(0)"
                         : "+v"(ra0), "+v"(ra1), "+v"(ra2), "+v"(ra3) :: "memory");
            WRITEBK(c + 2);
            ISSUE(min(c + 3, 16));           // chunk 16 = halo rows 64,65 (clamped)
        }

        asm volatile("s_waitcnt lgkmcnt(0)" ::: "memory");
        __builtin_amdgcn_s_barrier();        // NO vmcnt drain: prefetch survives

        // out(c): threads 0..127, one pixel each; mp parity c&1
        if (tid < 128) {
            const int r4 = tid >> 5, opx = tid & 31;
            float f0 = __builtin_bit_cast(float, (unsigned)mp[c & 1][0][r4][opx] << 16);
            float f1 = __builtin_bit_cast(float, (unsigned)mp[c & 1][1][r4][opx] << 16);
            float y  = dtanh2(fminf(f0, f1));
            const int oh = hbase + 4 * c + r4;
            const int ow = ow0 + opx;
            if (oh < OHH && ow < OWW)
                out[((size_t)n * OHH + oh) * OWW + ow] = y;
        }
    }
#undef ISSUE
#undef WRITEBK
}

extern "C" void kernel_launch(void* const* d_in, const int* in_sizes, int n_in,
                              void* d_out, int out_size, void* d_ws, size_t ws_size,
                              hipStream_t stream) {
    const float* x = (const float*)d_in[0];
    const float* w = (const float*)d_in[1];
    const float* b = (const float*)d_in[2];
    float* out     = (float*)d_out;
    ushort* wfrag  = (ushort*)d_ws;          // 18 KiB

    prep_weights<<<36, 256, 0, stream>>>(w, wfrag);
    dim3 grid(8, 4, 32);                     // (w-strip, h-quarter, n): 1024 blocks, 4/CU exact
    conv_min_tanh<<<grid, dim3(256, 1, 1), 0, stream>>>(x, wfrag, b, out);
}

// Round 20
// 52.071 us; speedup vs baseline: 1.0269x; 1.0269x over previous
//
#include <hip/hip_runtime.h>
#include <hip/hip_bf16.h>

typedef __attribute__((ext_vector_type(8)))  short short8;
typedef __attribute__((ext_vector_type(4)))  float f32x4;
typedef __attribute__((ext_vector_type(16))) float f32x16;

#define CIN   16
#define HH    256
#define WW    256
#define OHH   254
#define OWW   254
#define HW    (HH * WW)

// LDS row-ring: [2 cihalf][32 slot][36 w][8 ci] bf16, 16B cells (R7/R13-proven
// geometry: px stride 16B -> conflict-free b128). Half stride padded +16B.
#define SLOTU  (36 * 8)              // 288 ushorts per patch row
#define HALF_R (32 * SLOTU + 8)      // 9224 ushorts per ci-half  (36,896 B ring)

__device__ __forceinline__ ushort f2bf(float f) {
    unsigned u = __builtin_bit_cast(unsigned, f);
    unsigned r = (u + 0x7fffu + ((u >> 16) & 1u)) >> 16;
    return (ushort)r;
}

// fast tanh(tanh(x)): exp2-based (verified absmax 3.9e-3 in R1-R19)
__device__ __forceinline__ float dtanh2(float x) {
    const float K = 2.8853900817779268f;   // 2*log2(e)
    float xc = fminf(fmaxf(x, -9.0f), 9.0f);
    float e1 = __builtin_amdgcn_exp2f(K * xc);
    float t1 = 1.0f - 2.0f * __builtin_amdgcn_rcpf(e1 + 1.0f);
    float e2 = __builtin_amdgcn_exp2f(K * t1);
    return 1.0f - 2.0f * __builtin_amdgcn_rcpf(e2 + 1.0f);
}

// tree min over 16 accumulator elements (depth 4)
__device__ __forceinline__ float rmin16(f32x16 a) {
    float t0 = fminf(fminf(a[0],  a[1]),  fminf(a[2],  a[3]));
    float t1 = fminf(fminf(a[4],  a[5]),  fminf(a[6],  a[7]));
    float t2 = fminf(fminf(a[8],  a[9]),  fminf(a[10], a[11]));
    float t3 = fminf(fminf(a[12], a[13]), fminf(a[14], a[15]));
    return fminf(fminf(t0, t1), fminf(t2, t3));
}

// Weights fp32 OIHW [64][16][3][3] -> 32x32x16 A-fragments (R9-proven):
// wfrag[tap][j][lane][r]: channel row = j*32+(lane&31), ci = 8*(lane>>5)+r.
__global__ void prep_weights(const float* __restrict__ wsrc, ushort* __restrict__ wfrag) {
    int idx = blockIdx.x * 256 + threadIdx.x;
    if (idx >= 9216) return;
    int r    = idx & 7;
    int lane = (idx >> 3) & 63;
    int j    = (idx >> 9) & 1;
    int tap  = idx >> 10;                 // 0..8
    int ci   = 8 * (lane >> 5) + r;
    int co   = j * 32 + (lane & 31);
    int kh   = tap / 3, kw = tap - 3 * kh;
    wfrag[idx] = f2bf(wsrc[(co * CIN + ci) * 9 + kh * 3 + kw]);
}

// 128-row strips, 512 blocks = 2/CU zero-tail. 8-row chunks: 16 barriers/block
// (half of R16), 4 independent MFMA chains per wave. Raw s_barrier + lgkm-only
// (no vmcnt drain at barriers); single-chunk prefetch drained after compute.
__global__ __launch_bounds__(256, 2) void conv_min_tanh(
        const float* __restrict__ x, const ushort* __restrict__ wfrag,
        const float* __restrict__ bias, float* __restrict__ out) {
    __shared__ ushort ring[2 * HALF_R];      // 36,896 B
    __shared__ ushort mp[2][2][8][32];       // 2,048 B (parity-double-buffered)

    const int tid   = threadIdx.x;
    const int ow0   = blockIdx.x * 32;
    const int hbase = blockIdx.y * 128;      // half-strip base row
    const int n     = blockIdx.z;
    const float* xb = x + (size_t)n * CIN * HW;

    // ---- prologue: stage patch rows 0..9 (chunk 0's full window) inline ----
    auto stage_inline = [&](int pos) {       // pos = lr*36 + ciq*9 + w4, lr 0..9
        int lr_  = pos / 36;
        int rm_  = pos - lr_ * 36;
        int ciq_ = rm_ / 9;
        int w4_  = rm_ - ciq_ * 9;
        int hg  = min(hbase + lr_, HH - 1);
        int wg_ = min(ow0 + 4 * w4_, WW - 4);
        const float* src = xb + (size_t)(ciq_ * 4) * HW + hg * WW + wg_;
        f32x4 v0 = *reinterpret_cast<const f32x4*>(src);
        f32x4 v1 = *reinterpret_cast<const f32x4*>(src + HW);
        f32x4 v2 = *reinterpret_cast<const f32x4*>(src + 2 * HW);
        f32x4 v3 = *reinterpret_cast<const f32x4*>(src + 3 * HW);
        ushort* dst = &ring[(ciq_ >> 1) * HALF_R + (lr_ & 31) * SLOTU + (4 * w4_) * 8 + (ciq_ & 1) * 4];
#pragma unroll
        for (int e = 0; e < 4; ++e) {
            unsigned lo, hi;
            asm("v_cvt_pk_bf16_f32 %0, %1, %2" : "=v"(lo) : "v"(v0[e]), "v"(v1[e]));
            asm("v_cvt_pk_bf16_f32 %0, %1, %2" : "=v"(hi) : "v"(v2[e]), "v"(v3[e]));
            uint2 pk; pk.x = lo; pk.y = hi;
            *reinterpret_cast<uint2*>(dst + e * 8) = pk;
        }
    };
    stage_inline(tid);
    if (tid < 104) stage_inline(tid + 256);  // 360 positions = rows 0..9

    // ---- steady-state stage constants: 8-row chunk = 288 positions ----
    // ra: all 256 threads take pos=tid; rb: tid<32 take pos=256+tid (lr=7)
    const int lra  = tid / 36;               // 0..7
    const int rma  = tid - lra * 36;
    const int ciqa = rma / 9;
    const int w4a  = rma - ciqa * 9;
    const float* gba = xb + (size_t)(ciqa * 4) * HW + min(ow0 + 4 * w4a, WW - 4);
    ushort* sda = &ring[(ciqa >> 1) * HALF_R + (4 * w4a) * 8 + (ciqa & 1) * 4];
    const bool hasb = (tid < 32);
    const int rmb  = 4 + tid;                // lr=7
    const int ciqb = rmb / 9;
    const int w4b  = rmb - ciqb * 9;
    const float* gbb = xb + (size_t)(ciqb * 4) * HW + min(ow0 + 4 * w4b, WW - 4);
    ushort* sdb = &ring[(ciqb >> 1) * HALF_R + (4 * w4b) * 8 + (ciqb & 1) * 4];

    f32x4 ra0 = {}, ra1 = {}, ra2 = {}, ra3 = {};
    f32x4 rb0 = {}, rb1 = {}, rb2 = {}, rb3 = {};

    // STAGE(c): new patch rows for chunk c = 8c+2 .. 8c+9
#define ISSUE(cc)                                                              \
    {                                                                          \
        int hg = min(hbase + 8 * (cc) + 2 + lra, HH - 1);                      \
        const float* s_ = gba + hg * WW;                                       \
        asm volatile("global_load_dwordx4 %0, %1, off" : "=v"(ra0) : "v"(s_) : "memory");           \
        asm volatile("global_load_dwordx4 %0, %1, off" : "=v"(ra1) : "v"(s_ + HW) : "memory");      \
        asm volatile("global_load_dwordx4 %0, %1, off" : "=v"(ra2) : "v"(s_ + 2 * HW) : "memory");  \
        asm volatile("global_load_dwordx4 %0, %1, off" : "=v"(ra3) : "v"(s_ + 3 * HW) : "memory");  \
        if (hasb) {                                                            \
            int hg2 = min(hbase + 8 * (cc) + 2 + 7, HH - 1);                   \
            const float* t_ = gbb + hg2 * WW;                                  \
            asm volatile("global_load_dwordx4 %0, %1, off" : "=v"(rb0) : "v"(t_) : "memory");           \
            asm volatile("global_load_dwordx4 %0, %1, off" : "=v"(rb1) : "v"(t_ + HW) : "memory");      \
            asm volatile("global_load_dwordx4 %0, %1, off" : "=v"(rb2) : "v"(t_ + 2 * HW) : "memory");  \
            asm volatile("global_load_dwordx4 %0, %1, off" : "=v"(rb3) : "v"(t_ + 3 * HW) : "memory");  \
        }                                                                      \
    }

#define WRITEBK(cc)                                                            \
    {                                                                          \
        ushort* d_ = sda + ((8 * (cc) + 2 + lra) & 31) * SLOTU;                \
        _Pragma("unroll")                                                      \
        for (int e = 0; e < 4; ++e) {                                          \
            unsigned lo_, hi_;                                                 \
            asm("v_cvt_pk_bf16_f32 %0, %1, %2" : "=v"(lo_) : "v"(ra0[e]), "v"(ra1[e]));  \
            asm("v_cvt_pk_bf16_f32 %0, %1, %2" : "=v"(hi_) : "v"(ra2[e]), "v"(ra3[e]));  \
            uint2 pk_; pk_.x = lo_; pk_.y = hi_;                               \
            *reinterpret_cast<uint2*>(d_ + e * 8) = pk_;                       \
        }                                                                      \
        if (hasb) {                                                            \
            ushort* d2 = sdb + ((8 * (cc) + 9) & 31) * SLOTU;                  \
            _Pragma("unroll")                                                  \
            for (int e = 0; e < 4; ++e) {                                      \
                unsigned lo_, hi_;                                             \
                asm("v_cvt_pk_bf16_f32 %0, %1, %2" : "=v"(lo_) : "v"(rb0[e]), "v"(rb1[e]));  \
                asm("v_cvt_pk_bf16_f32 %0, %1, %2" : "=v"(hi_) : "v"(rb2[e]), "v"(rb3[e]));  \
                uint2 pk_; pk_.x = lo_; pk_.y = hi_;                           \
                *reinterpret_cast<uint2*>(d2 + e * 8) = pk_;                   \
            }                                                                  \
        }                                                                      \
    }

    ISSUE(1);                                // chunk 1 in flight during chunk 0

    // ---- weights (A-operand) + bias while loads fly ----
    const int lane  = tid & 63;
    const int wid   = tid >> 6;
    const int jw    = wid & 1;               // channel tile
    const int rq    = wid >> 1;              // row quad: rows rq*4..rq*4+3 of chunk
    const int px    = lane & 31;
    const int khalf = lane >> 5;
    short8 wf[9];
#pragma unroll
    for (int tap = 0; tap < 9; ++tap)
        wf[tap] = *reinterpret_cast<const short8*>(wfrag + ((tap * 2 + jw) * 64 + lane) * 8);
    f32x16 bi;                               // D row = (r&3)+8*(r>>2)+4*khalf
#pragma unroll
    for (int q4 = 0; q4 < 4; ++q4) {
        f32x4 b = *reinterpret_cast<const f32x4*>(bias + jw * 32 + 4 * khalf + 8 * q4);
#pragma unroll
        for (int s = 0; s < 4; ++s) bi[q4 * 4 + s] = b[s];
    }
    const ushort* bptr = &ring[khalf * HALF_R + px * 8];

    asm volatile("s_waitcnt lgkmcnt(0)" ::: "memory");
    __builtin_amdgcn_s_barrier();            // rows 0..9 ready; loads stay in flight

    // ---- 16 chunks of 8 rows: compute | drain+write+issue | barrier | out ----
#pragma unroll 2
    for (int c = 0; c < 16; ++c) {
        // 4 rows/wave, row-merged: 6 patch rows, 18 ds_reads, 36 MFMA, 4 chains
        {
            const int P0 = 8 * c + rq * 4;   // first patch row this wave touches
            f32x16 a0 = bi, a1 = bi, a2 = bi, a3 = bi;
#pragma unroll
            for (int t = 0; t < 6; ++t) {
                const ushort* rp = bptr + ((P0 + t) & 31) * SLOTU;
                short8 f0 = *reinterpret_cast<const short8*>(rp);
                short8 f1 = *reinterpret_cast<const short8*>(rp + 8);
                short8 f2 = *reinterpret_cast<const short8*>(rp + 16);
#define FEED(i)                                                                         \
                if (t - (i) >= 0 && t - (i) <= 2) {                                     \
                    a##i = __builtin_amdgcn_mfma_f32_32x32x16_bf16(wf[(t - (i)) * 3 + 0], f0, a##i, 0, 0, 0); \
                    a##i = __builtin_amdgcn_mfma_f32_32x32x16_bf16(wf[(t - (i)) * 3 + 1], f1, a##i, 0, 0, 0); \
                    a##i = __builtin_amdgcn_mfma_f32_32x32x16_bf16(wf[(t - (i)) * 3 + 2], f2, a##i, 0, 0, 0); \
                }
                FEED(0) FEED(1) FEED(2) FEED(3)
#undef FEED
            }
            float v0 = rmin16(a0), v1 = rmin16(a1), v2 = rmin16(a2), v3 = rmin16(a3);
            v0 = fminf(v0, __shfl_xor(v0, 32, 64));
            v1 = fminf(v1, __shfl_xor(v1, 32, 64));
            v2 = fminf(v2, __shfl_xor(v2, 32, 64));
            v3 = fminf(v3, __shfl_xor(v3, 32, 64));
            if (lane < 32) {
                mp[c & 1][jw][rq * 4 + 0][px] = f2bf(v0);
                mp[c & 1][jw][rq * 4 + 1][px] = f2bf(v1);
                mp[c & 1][jw][rq * 4 + 2][px] = f2bf(v2);
                mp[c & 1][jw][rq * 4 + 3][px] = f2bf(v3);
            }
        }

        // drain the single outstanding chunk (had full compute to land), write, reissue
        if (c < 15) {
            asm volatile("s_waitcnt vmcnt(0)"
                         : "+v"(ra0), "+v"(ra1), "+v"(ra2), "+v"(ra3),
                           "+v"(rb0), "+v"(rb1), "+v"(rb2), "+v"(rb3) :: "memory");
            WRITEBK(c + 1);
            if (c + 2 <= 15) ISSUE(c + 2);
        }

        asm volatile("s_waitcnt lgkmcnt(0)" ::: "memory");
        __builtin_amdgcn_s_barrier();        // NO vmcnt drain: prefetch survives

        // out(c): all 256 threads, one pixel each; mp parity c&1
        {
            const int r8 = tid >> 5, opx = tid & 31;
            float f0 = __builtin_bit_cast(float, (unsigned)mp[c & 1][0][r8][opx] << 16);
            float f1 = __builtin_bit_cast(float, (unsigned)mp[c & 1][1][r8][opx] << 16);
            float y  = dtanh2(fminf(f0, f1));
            const int oh = hbase + 8 * c + r8;
            const int ow = ow0 + opx;
            if (oh < OHH && ow < OWW)
                out[((size_t)n * OHH + oh) * OWW + ow] = y;
        }
    }
#undef ISSUE
#undef WRITEBK
}

extern "C" void kernel_launch(void* const* d_in, const int* in_sizes, int n_in,
                              void* d_out, int out_size, void* d_ws, size_t ws_size,
                              hipStream_t stream) {
    const float* x = (const float*)d_in[0];
    const float* w = (const float*)d_in[1];
    const float* b = (const float*)d_in[2];
    float* out     = (float*)d_out;
    ushort* wfrag  = (ushort*)d_ws;          // 18 KiB

    prep_weights<<<36, 256, 0, stream>>>(w, wfrag);
    dim3 grid(8, 2, 32);                     // (w-strip, h-half, n): 512 blocks, 2/CU
    conv_min_tanh<<<grid, dim3(256, 1, 1), 0, stream>>>(x, wfrag, b, out);
}